// Round 1
// baseline (289.083 us; speedup 1.0000x reference)
//
#include <hip/hip_runtime.h>
#include <hip/hip_bf16.h>
#include <math.h>

// Problem constants
#define P_TOTAL 18378
// param breakpoints (floats): w1 [0,400), b1 [400,416), w2 [416,13216),
// b2 [13216,13248), w3 [13248,18368), b3 [18368,18378)

__device__ __forceinline__ unsigned short f2bf(float f) {
    union { float f; unsigned u; } v; v.f = f;
    unsigned r = v.u + 0x7fffu + ((v.u >> 16) & 1u);
    return (unsigned short)(r >> 16);
}
__device__ __forceinline__ float bf2f(unsigned short h) {
    union { unsigned u; float f; } v; v.u = ((unsigned)h) << 16;
    return v.f;
}

// ---------------- Kernel 1: conv1 (16x1x5x5) + ReLU + maxpool2x2 ----------------
// grid = 64*128 blocks (one per (init, image)), block = 192 = 16co x 12py tasks.
// Each thread computes conv rows y0=2py, y0+1 (24 cols each) -> 12 pooled outputs.
__global__ __launch_bounds__(192) void conv1_kernel(const float* __restrict__ params,
                                                    const float* __restrict__ batch,
                                                    unsigned short* __restrict__ act1) {
    __shared__ float img[784];   // 28x28
    __shared__ float w1s[400];
    __shared__ float b1s[16];
    int b = blockIdx.x;
    int i = b >> 7;     // init
    int j = b & 127;    // image
    int t = threadIdx.x;
    const float* ip = batch + j * 784;
    for (int k = t; k < 784; k += 192) img[k] = ip[k];
    const float* pp = params + (size_t)i * P_TOTAL;
    for (int k = t; k < 400; k += 192) w1s[k] = pp[k];
    if (t < 16) b1s[t] = pp[400 + t];
    __syncthreads();

    int co = t / 12;        // 0..15
    int py = t - co * 12;   // 0..11
    float wr[25];
#pragma unroll
    for (int k = 0; k < 25; ++k) wr[k] = w1s[co * 25 + k];
    float bias = b1s[co];

    float c0[24], c1[24];
#pragma unroll
    for (int x = 0; x < 24; ++x) { c0[x] = 0.f; c1[x] = 0.f; }
    int y0 = 2 * py;
#pragma unroll
    for (int r = 0; r < 6; ++r) {
        float row[28];
        const float* rp = img + (y0 + r) * 28;
#pragma unroll
        for (int x = 0; x < 28; ++x) row[x] = rp[x];
        if (r < 5) {
#pragma unroll
            for (int kx = 0; kx < 5; ++kx) {
                float wv = wr[r * 5 + kx];
#pragma unroll
                for (int x = 0; x < 24; ++x) c0[x] = fmaf(row[x + kx], wv, c0[x]);
            }
        }
        if (r >= 1) {
#pragma unroll
            for (int kx = 0; kx < 5; ++kx) {
                float wv = wr[(r - 1) * 5 + kx];
#pragma unroll
                for (int x = 0; x < 24; ++x) c1[x] = fmaf(row[x + kx], wv, c1[x]);
            }
        }
    }
    // ReLU(conv+bias) then 2x2 maxpool == max(0, max4(conv)+bias)
    unsigned short* op = act1 + (((size_t)(i * 128 + j)) * 16 + co) * 144 + py * 12;
#pragma unroll
    for (int px = 0; px < 12; ++px) {
        float v = fmaxf(fmaxf(c0[2 * px], c0[2 * px + 1]), fmaxf(c1[2 * px], c1[2 * px + 1]));
        op[px] = f2bf(fmaxf(v + bias, 0.f));
    }
}

// ---------------- Kernel 2: conv2 (32x16x5x5) + ReLU + maxpool2x2 ----------------
// grid = 64 inits * 16 groups * 2 co-halves = 2048 blocks, block = 256.
// Block stages 16 co (one half) weights in LDS (stride 401 -> conflict-free) and
// 4 images of act1 per pass (2 passes = 8 images per block).
// Thread task = (image q, co_l, py): conv rows 2py,2py+1 over x=0..7, cin loop.
__global__ __launch_bounds__(256) void conv2_kernel(const float* __restrict__ params,
                                                    const unsigned short* __restrict__ act1,
                                                    unsigned short* __restrict__ act2) {
    __shared__ float w2s[16 * 401];   // 25664 B
    __shared__ float b2s[16];
    __shared__ float a1s[4 * 2304];   // 36864 B ; total ~62.6 KB < 64 KB
    int b = blockIdx.x;
    int i = b >> 5;           // init
    int gh = b & 31;
    int g = gh >> 1;          // group 0..15 (8 images each)
    int half = gh & 1;        // co half
    int t = threadIdx.x;

    const float* wsrc = params + (size_t)i * P_TOTAL + 416 + half * 16 * 400;
    for (int c = 0; c < 16; ++c)
        for (int k = t; k < 400; k += 256)
            w2s[c * 401 + k] = wsrc[c * 400 + k];
    if (t < 16) b2s[t] = params[(size_t)i * P_TOTAL + 13216 + half * 16 + t];

    int q = t >> 6;           // image within pass (== wave id)
    int lane = t & 63;
    int co_l = lane >> 2;     // 0..15
    int py = lane & 3;        // 0..3
    int y0 = 2 * py;
    const float* wbase = w2s + co_l * 401;

    for (int s = 0; s < 2; ++s) {
        int jbase = g * 8 + s * 4;
        __syncthreads();      // protects w2s (first iter) and a1s reuse
        const unsigned short* src = act1 + ((size_t)i * 128 + jbase) * 2304;
        for (int k = t; k < 9216; k += 256) a1s[k] = bf2f(src[k]);
        __syncthreads();

        const float* ap = a1s + q * 2304;
        float c0[8], c1[8];
#pragma unroll
        for (int x = 0; x < 8; ++x) { c0[x] = 0.f; c1[x] = 0.f; }
#pragma unroll 1
        for (int cin = 0; cin < 16; ++cin) {
            float wr[25];
#pragma unroll
            for (int k = 0; k < 25; ++k) wr[k] = wbase[cin * 25 + k];
            const float* abase = ap + cin * 144 + y0 * 12;
#pragma unroll
            for (int r = 0; r < 6; ++r) {
                float row[12];
#pragma unroll
                for (int x = 0; x < 12; ++x) row[x] = abase[r * 12 + x];
                if (r < 5) {
#pragma unroll
                    for (int kx = 0; kx < 5; ++kx) {
                        float wv = wr[r * 5 + kx];
#pragma unroll
                        for (int x = 0; x < 8; ++x) c0[x] = fmaf(row[x + kx], wv, c0[x]);
                    }
                }
                if (r >= 1) {
#pragma unroll
                    for (int kx = 0; kx < 5; ++kx) {
                        float wv = wr[(r - 1) * 5 + kx];
#pragma unroll
                        for (int x = 0; x < 8; ++x) c1[x] = fmaf(row[x + kx], wv, c1[x]);
                    }
                }
            }
        }
        float bias = b2s[co_l];
        int j = jbase + q;
        unsigned short* op = act2 + ((size_t)i * 128 + j) * 512 + (half * 16 + co_l) * 16 + py * 4;
#pragma unroll
        for (int px = 0; px < 4; ++px) {
            float v = fmaxf(fmaxf(c0[2 * px], c0[2 * px + 1]), fmaxf(c1[2 * px], c1[2 * px + 1]));
            op[px] = f2bf(fmaxf(v + bias, 0.f));
        }
    }
}

// ---------------- Kernel 3: dense (10x512) + log_softmax ----------------
// One wave per (init, image) pair: 8192 waves, block=256 -> grid=2048.
__global__ __launch_bounds__(256) void dense_kernel(const float* __restrict__ params,
                                                    const unsigned short* __restrict__ act2,
                                                    float* __restrict__ out) {
    int wid = blockIdx.x * 4 + (threadIdx.x >> 6);  // pair 0..8191
    int lane = threadIdx.x & 63;
    int i = wid >> 7;

    const unsigned short* xp = act2 + (size_t)wid * 512 + lane * 8;
    uint4 u = *(const uint4*)xp;   // 8 bf16, 16B aligned
    float xr[8];
    xr[0] = bf2f((unsigned short)(u.x & 0xffffu)); xr[1] = bf2f((unsigned short)(u.x >> 16));
    xr[2] = bf2f((unsigned short)(u.y & 0xffffu)); xr[3] = bf2f((unsigned short)(u.y >> 16));
    xr[4] = bf2f((unsigned short)(u.z & 0xffffu)); xr[5] = bf2f((unsigned short)(u.z >> 16));
    xr[6] = bf2f((unsigned short)(u.w & 0xffffu)); xr[7] = bf2f((unsigned short)(u.w >> 16));

    const float* wp = params + (size_t)i * P_TOTAL + 13248 + lane * 8;
    float acc[10];
#pragma unroll
    for (int o = 0; o < 10; ++o) {
        const float* w = wp + o * 512;
        float a = 0.f;
#pragma unroll
        for (int k = 0; k < 8; ++k) a = fmaf(xr[k], w[k], a);
#pragma unroll
        for (int d = 32; d >= 1; d >>= 1) a += __shfl_xor(a, d, 64);
        acc[o] = a;
    }
    const float* bp = params + (size_t)i * P_TOTAL + 18368;
    float m = -3.4e38f;
#pragma unroll
    for (int o = 0; o < 10; ++o) { acc[o] += bp[o]; m = fmaxf(m, acc[o]); }
    float ssum = 0.f;
#pragma unroll
    for (int o = 0; o < 10; ++o) ssum += expf(acc[o] - m);
    float ls = logf(ssum) + m;
    if (lane == 0) {
        float* op = out + (size_t)wid * 10;
#pragma unroll
        for (int o = 0; o < 10; ++o) op[o] = acc[o] - ls;
    }
}

extern "C" void kernel_launch(void* const* d_in, const int* in_sizes, int n_in,
                              void* d_out, int out_size, void* d_ws, size_t ws_size,
                              hipStream_t stream) {
    const float* params = (const float*)d_in[0];   // (64, 18378) fp32
    const float* batch  = (const float*)d_in[1];   // (128, 1, 28, 28) fp32
    float* out = (float*)d_out;                    // (64, 128, 10) fp32

    // workspace: act1 bf16 (64*128*16*12*12 = 18,874,368 elems = 37.75 MB)
    //            act2 bf16 (64*128*512    =  4,194,304 elems =  8.39 MB)
    // total ~46.1 MB
    unsigned short* act1 = (unsigned short*)d_ws;
    unsigned short* act2 = act1 + (size_t)64 * 128 * 2304;

    conv1_kernel<<<8192, 192, 0, stream>>>(params, batch, act1);
    conv2_kernel<<<2048, 256, 0, stream>>>(params, act1, act2);
    dense_kernel<<<2048, 256, 0, stream>>>(params, act2, out);
}

// Round 2
// 154.776 us; speedup vs baseline: 1.8677x; 1.8677x over previous
//
#include <hip/hip_runtime.h>
#include <hip/hip_bf16.h>
#include <math.h>

// Problem constants
#define P_TOTAL 18378
// param breakpoints (floats): w1 [0,400), b1 [400,416), w2 [416,13216),
// b2 [13216,13248), w3 [13248,18368), b3 [18368,18378)

typedef __attribute__((ext_vector_type(8))) short short8;
typedef __attribute__((ext_vector_type(16))) float float16;

__device__ __forceinline__ unsigned short f2bf(float f) {
    union { float f; unsigned u; } v; v.f = f;
    unsigned r = v.u + 0x7fffu + ((v.u >> 16) & 1u);
    return (unsigned short)(r >> 16);
}
__device__ __forceinline__ float bf2f(unsigned short h) {
    union { unsigned u; float f; } v; v.u = ((unsigned)h) << 16;
    return v.f;
}

// ---------------- Kernel 0: swizzle conv2 weights to bf16 [init][tap][co][cin] ----------------
__global__ __launch_bounds__(256) void wswz_kernel(const float* __restrict__ params,
                                                   unsigned short* __restrict__ wswz) {
    int i = blockIdx.x;
    const float* w2 = params + (size_t)i * P_TOTAL + 416;   // [co=32][cin=16][ky=5][kx=5]
    unsigned short* dst = wswz + (size_t)i * 12800;
    for (int k = threadIdx.x; k < 12800; k += 256) {
        int co = k / 400;
        int r = k - co * 400;
        int cin = r / 25;
        int s = r - cin * 25;   // s = ky*5+kx
        dst[(s * 32 + co) * 16 + cin] = f2bf(w2[k]);
    }
}

// ---------------- Kernel 1: conv1 (16x1x5x5) + ReLU + maxpool2x2 ----------------
// grid = 64*128 blocks (one per (init, image)), block = 192 = 12py x 16co tasks.
// Writes act1 CHANNELS-LAST: [pair][pix=py*12+px][cin=16] bf16.
__global__ __launch_bounds__(192) void conv1_kernel(const float* __restrict__ params,
                                                    const float* __restrict__ batch,
                                                    unsigned short* __restrict__ act1) {
    __shared__ float img[784];   // 28x28
    __shared__ float w1s[400];
    __shared__ float b1s[16];
    int b = blockIdx.x;
    int i = b >> 7;     // init
    int j = b & 127;    // image
    int t = threadIdx.x;
    const float* ip = batch + j * 784;
    for (int k = t; k < 784; k += 192) img[k] = ip[k];
    const float* pp = params + (size_t)i * P_TOTAL;
    for (int k = t; k < 400; k += 192) w1s[k] = pp[k];
    if (t < 16) b1s[t] = pp[400 + t];
    __syncthreads();

    int co = t & 15;        // 0..15  (co minor -> act1 stores land in 32B runs)
    int py = t >> 4;        // 0..11
    float wr[25];
#pragma unroll
    for (int k = 0; k < 25; ++k) wr[k] = w1s[co * 25 + k];
    float bias = b1s[co];

    float c0[24], c1[24];
#pragma unroll
    for (int x = 0; x < 24; ++x) { c0[x] = 0.f; c1[x] = 0.f; }
    int y0 = 2 * py;
#pragma unroll
    for (int r = 0; r < 6; ++r) {
        float row[28];
        const float* rp = img + (y0 + r) * 28;
#pragma unroll
        for (int x = 0; x < 28; ++x) row[x] = rp[x];
        if (r < 5) {
#pragma unroll
            for (int kx = 0; kx < 5; ++kx) {
                float wv = wr[r * 5 + kx];
#pragma unroll
                for (int x = 0; x < 24; ++x) c0[x] = fmaf(row[x + kx], wv, c0[x]);
            }
        }
        if (r >= 1) {
#pragma unroll
            for (int kx = 0; kx < 5; ++kx) {
                float wv = wr[(r - 1) * 5 + kx];
#pragma unroll
                for (int x = 0; x < 24; ++x) c1[x] = fmaf(row[x + kx], wv, c1[x]);
            }
        }
    }
    // channels-last store: [pair][py*12+px][co]
    unsigned short* op = act1 + ((size_t)(i * 128 + j) * 144 + py * 12) * 16 + co;
#pragma unroll
    for (int px = 0; px < 12; ++px) {
        float v = fmaxf(fmaxf(c0[2 * px], c0[2 * px + 1]), fmaxf(c1[2 * px], c1[2 * px + 1]));
        op[px * 16] = f2bf(fmaxf(v + bias, 0.f));
    }
}

// ---------------- Kernel 2: conv2 via MFMA implicit GEMM ----------------
// Decompose conv as 25 taps of K=16(cin) GEMM: one mfma_f32_32x32x16_bf16 per tap.
// Block = 256 thr (4 waves) = one (init, 4-image group). Wave w computes image w:
// C = 32co x 64pix as two 32x32 acc tiles. A (weights) and B (act1, channels-last,
// LDS pixel stride 24 elems -> conflict-free b128) are single ds_read_b128 per tap.
#define A1_PIX_STRIDE 24        // elems (48 B) in LDS
#define IMG_LDS (144 * 24)      // 3456 elems = 6912 B per image
__global__ __launch_bounds__(256) void conv2_mfma_kernel(
        const float* __restrict__ params,
        const unsigned short* __restrict__ act1,   // [pair][144][16] bf16
        const unsigned short* __restrict__ wswz,   // [init][25][32][16] bf16
        unsigned short* __restrict__ act2) {       // [pair][32co][16pp] bf16
    __shared__ char smem[58880];
    unsigned short* wlds = (unsigned short*)smem;            // 12800 elems = 25600 B
    unsigned short* a1s  = (unsigned short*)(smem + 25600);  // 4 * 3456 elems = 27648 B
    float* scratch       = (float*)(smem + 25600);           // 4 * 2080 f32 = 33280 B (reuses a1s)

    int b = blockIdx.x;
    int i = b >> 5;           // init
    int g = b & 31;           // image group
    int jbase = g * 4;
    int t = threadIdx.x;
    int w = t >> 6;           // wave = image index within group
    int lane = t & 63;

    // stage swizzled weights: 25600 B = 1600 x 16B, straight copy
    {
        const uint4* src = (const uint4*)(wswz + (size_t)i * 12800);
        uint4* dst = (uint4*)wlds;
        for (int k = t; k < 1600; k += 256) dst[k] = src[k];
    }
    // stage act1 (4 images) with pad: 1152 x 16B chunks
    {
        for (int k = t; k < 1152; k += 256) {
            int img = k / 288;             // 288 chunks per image
            int rem = k - img * 288;
            int pix = rem >> 1;
            int h   = rem & 1;
            const uint4* src = (const uint4*)(act1 +
                ((size_t)(i * 128 + jbase + img) * 144 + pix) * 16 + h * 8);
            uint4* dst = (uint4*)(a1s + img * IMG_LDS + pix * A1_PIX_STRIDE + h * 8);
            *dst = *src;
        }
    }
    __syncthreads();

    int n = lane & 31;        // A: co row; B: pixel col within tile
    int h = lane >> 5;        // k-half (8 cin each)
    // A frag: wlds[(tap*32 + co)*16 + h*8], tap offset = 1024 B
    const short8* aptr = (const short8*)(wlds + n * 16 + h * 8);
    // B frags: pixel (y,x); tile0 pix = n (y=0..3), tile1 pix = 32+n (y=4..7)
    int y0 = n >> 3, x0 = n & 7;
    const unsigned short* bbase = a1s + w * IMG_LDS;
    const short8* bptr0 = (const short8*)(bbase + ((y0    ) * 12 + x0) * A1_PIX_STRIDE + h * 8);
    const short8* bptr1 = (const short8*)(bbase + ((y0 + 4) * 12 + x0) * A1_PIX_STRIDE + h * 8);

    float16 acc0 = {};
    float16 acc1 = {};
#pragma unroll
    for (int ky = 0; ky < 5; ++ky) {
#pragma unroll
        for (int kx = 0; kx < 5; ++kx) {
            int tap = ky * 5 + kx;
            short8 af = aptr[tap * 64];               // +tap*1024 B
            int bo = (ky * 12 + kx) * 3;              // *48 B in short8 units
            short8 b0 = bptr0[bo];
            short8 b1 = bptr1[bo];
            acc0 = __builtin_amdgcn_mfma_f32_32x32x16_bf16(af, b0, acc0, 0, 0, 0);
            acc1 = __builtin_amdgcn_mfma_f32_32x32x16_bf16(af, b1, acc1, 0, 0, 0);
        }
    }
    __syncthreads();   // all waves done reading a1s before scratch overwrites it

    // spill acc to LDS (stride-65 pad: bank = (co+pix)%32, conflict-free)
    float* sw = scratch + w * 2080;
#pragma unroll
    for (int r = 0; r < 16; ++r) {
        int co = (r & 3) + 8 * (r >> 2) + 4 * h;      // C/D row mapping (verified m74/m101)
        sw[co * 65 + n]      = acc0[r];
        sw[co * 65 + 32 + n] = acc1[r];
    }
    // same-wave LDS ordering -> no barrier needed before re-read

    // pool 2x2 + bias + ReLU + bf16, coalesced uint4 store
    int co2 = lane >> 1;                  // 0..31
    int ppb = (lane & 1) * 8;             // pooled-pixel base
    float bias = params[(size_t)i * P_TOTAL + 13216 + co2];
    unsigned short outv[8] __attribute__((aligned(16)));
#pragma unroll
    for (int it = 0; it < 8; ++it) {
        int pp = ppb + it;
        int py = pp >> 2, px = pp & 3;
        const float* s = sw + co2 * 65 + (py * 2) * 8 + px * 2;
        float v = fmaxf(fmaxf(s[0], s[1]), fmaxf(s[8], s[9]));
        outv[it] = f2bf(fmaxf(v + bias, 0.f));
    }
    int j = jbase + w;
    uint4* op = (uint4*)(act2 + ((size_t)i * 128 + j) * 512 + co2 * 16 + ppb);
    *op = *(const uint4*)outv;
}

// ---------------- Kernel 3: dense (10x512) + log_softmax ----------------
// One wave per (init, image) pair: 8192 waves, block=256 -> grid=2048.
__global__ __launch_bounds__(256) void dense_kernel(const float* __restrict__ params,
                                                    const unsigned short* __restrict__ act2,
                                                    float* __restrict__ out) {
    int wid = blockIdx.x * 4 + (threadIdx.x >> 6);  // pair 0..8191
    int lane = threadIdx.x & 63;
    int i = wid >> 7;

    const unsigned short* xp = act2 + (size_t)wid * 512 + lane * 8;
    uint4 u = *(const uint4*)xp;   // 8 bf16, 16B aligned
    float xr[8];
    xr[0] = bf2f((unsigned short)(u.x & 0xffffu)); xr[1] = bf2f((unsigned short)(u.x >> 16));
    xr[2] = bf2f((unsigned short)(u.y & 0xffffu)); xr[3] = bf2f((unsigned short)(u.y >> 16));
    xr[4] = bf2f((unsigned short)(u.z & 0xffffu)); xr[5] = bf2f((unsigned short)(u.z >> 16));
    xr[6] = bf2f((unsigned short)(u.w & 0xffffu)); xr[7] = bf2f((unsigned short)(u.w >> 16));

    const float* wp = params + (size_t)i * P_TOTAL + 13248 + lane * 8;
    float acc[10];
#pragma unroll
    for (int o = 0; o < 10; ++o) {
        const float* wv = wp + o * 512;
        float a = 0.f;
#pragma unroll
        for (int k = 0; k < 8; ++k) a = fmaf(xr[k], wv[k], a);
#pragma unroll
        for (int d = 32; d >= 1; d >>= 1) a += __shfl_xor(a, d, 64);
        acc[o] = a;
    }
    const float* bp = params + (size_t)i * P_TOTAL + 18368;
    float m = -3.4e38f;
#pragma unroll
    for (int o = 0; o < 10; ++o) { acc[o] += bp[o]; m = fmaxf(m, acc[o]); }
    float ssum = 0.f;
#pragma unroll
    for (int o = 0; o < 10; ++o) ssum += expf(acc[o] - m);
    float ls = logf(ssum) + m;
    if (lane == 0) {
        float* op = out + (size_t)wid * 10;
#pragma unroll
        for (int o = 0; o < 10; ++o) op[o] = acc[o] - ls;
    }
}

extern "C" void kernel_launch(void* const* d_in, const int* in_sizes, int n_in,
                              void* d_out, int out_size, void* d_ws, size_t ws_size,
                              hipStream_t stream) {
    const float* params = (const float*)d_in[0];   // (64, 18378) fp32
    const float* batch  = (const float*)d_in[1];   // (128, 1, 28, 28) fp32
    float* out = (float*)d_out;                    // (64, 128, 10) fp32

    // workspace layout (all 16B aligned):
    //   act1: 64*128*144*16 bf16 = 18,874,368 elems = 37,748,736 B
    //   act2: 64*128*512 bf16    =  4,194,304 elems =  8,388,608 B
    //   wswz: 64*25*32*16 bf16   =    819,200 elems =  1,638,400 B
    unsigned short* act1 = (unsigned short*)d_ws;
    unsigned short* act2 = act1 + (size_t)64 * 128 * 2304;
    unsigned short* wswz = act2 + (size_t)64 * 128 * 512;

    wswz_kernel<<<64, 256, 0, stream>>>(params, wswz);
    conv1_kernel<<<8192, 192, 0, stream>>>(params, batch, act1);
    conv2_mfma_kernel<<<2048, 256, 0, stream>>>(params, act1, wswz, act2);
    dense_kernel<<<2048, 256, 0, stream>>>(params, act2, out);
}